// Round 1
// baseline (180.444 us; speedup 1.0000x reference)
//
#include <hip/hip_runtime.h>

// Batched 3D affine spatial transformer: vol [B=4,160,192,160,1] fp32, trf [4,4,4] fp32.
// R5: attack the latency-bound profile (R4: no pipe >40%, VGPR_Count=16 proves the
// compiler serialized the gathers to ~2 in flight).
//  (a) 4 voxels/thread along d; ALL 16 gather loads issued in a load phase, pinned
//      above the consume phase with sched_barrier(0) -> ~16 loads in flight/wave.
//  (b) XCD-contiguous block swizzle (NWG=19200 % 8 == 0, bijective): each XCD's
//      concurrent blocks share a ~10-plane input slab (~1.3 MB < 4 MB L2) so the
//      gathers hit the local L2 instead of L3.
constexpr int D = 160, H = 192, W = 160, B = 4;
constexpr int V  = D * H * W;
constexpr int HW = H * W;
constexpr int VPT = 4;                     // voxels per thread along d
constexpr int GX  = (H / 8) * (W / 32);    // 24*5 = 120 blocks in the h/w plane
constexpr int GY  = D / VPT;               // 40
constexpr int NWG = GX * GY * B;           // 19200
constexpr int NXCD = 8;
constexpr int CPX  = NWG / NXCD;           // 2400 (exact)

struct DimS { int i0; float w0; };

// Equivalent to neuron.utils interpn clipping:
//   c = clip(loc,0,max); i0 = min((int)c, max-1); i1 = i0+1 (always in-bounds);
//   w0 = (i0+1) - c. Interior/low-clip/high-clip all match reference (verified R3).
__device__ __forceinline__ DimS prep(float loc, float maxv, int maxi) {
    float c  = fminf(fmaxf(loc, 0.0f), maxv);
    int  i0  = min((int)c, maxi - 1);
    DimS s;
    s.i0 = i0;
    s.w0 = (float)(i0 + 1) - c;
    return s;
}

__device__ __forceinline__ float2 ld2(const float* __restrict__ p) {
    float2 v;
    __builtin_memcpy(&v, p, 8);
    return v;
}

__global__ __launch_bounds__(256) void st_affine_kernel(
        const float* __restrict__ vol, const float* __restrict__ trf,
        float* __restrict__ out) {
    // ---- XCD-contiguous swizzle (hardware assigns XCD = linear_id % 8) ----
    const int id  = blockIdx.x;
    const int nid = (id & (NXCD - 1)) * CPX + (id >> 3);   // bijective since NWG%8==0
    const int bz  = nid / (GX * GY);                       // batch
    const int rem = nid - bz * (GX * GY);
    const int by  = rem / GX;                              // d-block
    const int bx  = rem - by * GX;                         // h/w-block

    const int d0   = by * VPT;
    const int hblk = bx / 5;
    const int wblk = bx - hblk * 5;
    const int w = wblk * 32 + threadIdx.x;
    const int h = hblk * 8  + threadIdx.y;

    const float* __restrict__ A = trf + bz * 16;   // wave-uniform -> scalar loads
    const float a00 = A[0], a01 = A[1], a02 = A[2],  a03 = A[3];
    const float a10 = A[4], a11 = A[5], a12 = A[6],  a13 = A[7];
    const float a20 = A[8], a21 = A[9], a22 = A[10], a23 = A[11];

    constexpr float cd = (D - 1) * 0.5f;
    constexpr float ch = (H - 1) * 0.5f;
    constexpr float cw = (W - 1) * 0.5f;

    const float md = (float)d0 - cd;
    const float mh = (float)h  - ch;
    const float mw = (float)w  - cw;

    // Sample location of voxel k (d0+k) = loc0 + k * column0(A).
    float ld = cd + fmaf(a00, md, fmaf(a01, mh, fmaf(a02, mw, a03)));
    float lh = ch + fmaf(a10, md, fmaf(a11, mh, fmaf(a12, mw, a13)));
    float lw = cw + fmaf(a20, md, fmaf(a21, mh, fmaf(a22, mw, a23)));

    const float* __restrict__ vb = vol + (size_t)bz * V;

    DimS sd[VPT], sh[VPT], sw[VPT];
    float2 v00[VPT], v01[VPT], v10[VPT], v11[VPT];

    // ---- Phase 1: all address math + ALL 16 gather loads issued ----
#pragma unroll
    for (int k = 0; k < VPT; ++k) {
        sd[k] = prep(ld, (float)(D - 1), D - 1);
        sh[k] = prep(lh, (float)(H - 1), H - 1);
        sw[k] = prep(lw, (float)(W - 1), W - 1);
        const float* p = vb + ((sd[k].i0 * H + sh[k].i0) * W + sw[k].i0);
        v00[k] = ld2(p);
        v01[k] = ld2(p + W);
        v10[k] = ld2(p + HW);
        v11[k] = ld2(p + HW + W);
        ld += a00; lh += a10; lw += a20;
    }
    // Hard fence: loads may NOT be sunk below this point (the R4 kernel's
    // VGPR_Count=16 shows the scheduler otherwise serializes them).
    __builtin_amdgcn_sched_barrier(0);

    // ---- Phase 2: consume (counted vmcnt keeps later loads in flight) ----
    float* ob = out + (size_t)bz * V + (size_t)h * W + w;
#pragma unroll
    for (int k = 0; k < VPT; ++k) {
        const float pd00 = fmaf(sw[k].w0, v00[k].x - v00[k].y, v00[k].y);
        const float pd01 = fmaf(sw[k].w0, v01[k].x - v01[k].y, v01[k].y);
        const float pd10 = fmaf(sw[k].w0, v10[k].x - v10[k].y, v10[k].y);
        const float pd11 = fmaf(sw[k].w0, v11[k].x - v11[k].y, v11[k].y);
        const float q0 = fmaf(sh[k].w0, pd00 - pd01, pd01);
        const float q1 = fmaf(sh[k].w0, pd10 - pd11, pd11);
        const float r  = fmaf(sd[k].w0, q0 - q1, q1);
        __builtin_nontemporal_store(r, ob + (size_t)(d0 + k) * HW);
    }
}

extern "C" void kernel_launch(void* const* d_in, const int* in_sizes, int n_in,
                              void* d_out, int out_size, void* d_ws, size_t ws_size,
                              hipStream_t stream) {
    const float* vol = (const float*)d_in[0];
    const float* trf = (const float*)d_in[1];
    float* out = (float*)d_out;

    dim3 grid(NWG, 1, 1);
    dim3 block(32, 8, 1);
    st_affine_kernel<<<grid, block, 0, stream>>>(vol, trf, out);
}

// Round 2
// 161.153 us; speedup vs baseline: 1.1197x; 1.1197x over previous
//
#include <hip/hip_runtime.h>

// Batched 3D affine spatial transformer: vol [B=4,160,192,160,1] fp32, trf [4,4,4] fp32.
// R6: R5's 16-deep load batching did NOT help (dur 73->79, VGPR=32 proves loads were
// batched) -> not latency-bound; the divergent 8B gathers are grinding the per-CU
// L1/TA line-service pipe. Fix: stage the block's input slab into LDS with coalesced
// async global_load_lds rows (affine near-identity -> 32x8x4 output tile needs only a
// ~37x11x7 input slab), then gather the 8 corners from LDS. Slab bbox is block-uniform
// (affine -> extremes at tile corners); blocks exceeding the 14x14x40 cap fall back to
// the R4-verified global path (identical arithmetic).
constexpr int D = 160, H = 192, W = 160, B = 4;
constexpr int V  = D * H * W;
constexpr int HW = H * W;
constexpr int VPT = 4;                 // output voxels per thread along d
constexpr int TW  = 32, TH = 8;        // output tile in (w,h); block = (32,8)
constexpr int GXW = W / TW;            // 5
constexpr int GXH = H / TH;            // 24
constexpr int SD_CAP = 14, SH_CAP = 14, SW_CAP = 40;
constexpr int PLANE = SH_CAP * SW_CAP;            // 560 floats
constexpr int LDS_FLOATS = SD_CAP * PLANE;        // 7840 floats = 31360 B -> 5 blk/CU

struct DimS { int i0; float w0; };

// Equivalent to neuron.utils interpn clipping (verified R3):
//   c = clip(loc,0,max); i0 = min((int)c, maxi-1); i1 = i0+1; w0 = (i0+1) - c.
__device__ __forceinline__ DimS prep(float loc, float maxv, int maxi) {
    float c  = fminf(fmaxf(loc, 0.0f), maxv);
    int  i0  = min((int)c, maxi - 1);
    DimS s;
    s.i0 = i0;
    s.w0 = (float)(i0 + 1) - c;
    return s;
}

__device__ __forceinline__ float lerp3(DimS sd, DimS sh, DimS sw,
                                       float2 v00, float2 v01,
                                       float2 v10, float2 v11) {
    const float pd00 = fmaf(sw.w0, v00.x - v00.y, v00.y);
    const float pd01 = fmaf(sw.w0, v01.x - v01.y, v01.y);
    const float pd10 = fmaf(sw.w0, v10.x - v10.y, v10.y);
    const float pd11 = fmaf(sw.w0, v11.x - v11.y, v11.y);
    const float q0 = fmaf(sh.w0, pd00 - pd01, pd01);
    const float q1 = fmaf(sh.w0, pd10 - pd11, pd11);
    return fmaf(sd.w0, q0 - q1, q1);
}

__device__ __forceinline__ float trilerp_g(const float* __restrict__ vb,
                                           DimS sd, DimS sh, DimS sw) {
    const float* p0 = vb + ((sd.i0 * H + sh.i0) * W + sw.i0);
    float2 v00, v01, v10, v11;
    __builtin_memcpy(&v00, p0,          8);
    __builtin_memcpy(&v01, p0 + W,      8);
    __builtin_memcpy(&v10, p0 + HW,     8);
    __builtin_memcpy(&v11, p0 + HW + W, 8);
    return lerp3(sd, sh, sw, v00, v01, v10, v11);
}

// Async global->LDS, 4B/lane. LDS dest is wave-uniform base + lane*4 (HW rule);
// inactive lanes neither load nor write.
__device__ __forceinline__ void gload_lds_row(const float* g, float* l) {
    __builtin_amdgcn_global_load_lds(
        (const __attribute__((address_space(1))) void*)g,
        (__attribute__((address_space(3))) void*)l,
        4, 0, 0);
}

__global__ __launch_bounds__(256) void st_affine_kernel(
        const float* __restrict__ vol, const float* __restrict__ trf,
        float* __restrict__ out) {
    __shared__ float sm[LDS_FLOATS];

    const int b  = blockIdx.z;
    const int d0 = blockIdx.y * VPT;
    const int hblk = blockIdx.x / GXW;
    const int wblk = blockIdx.x - hblk * GXW;
    const int w0 = wblk * TW, h0 = hblk * TH;
    const int w  = w0 + threadIdx.x;
    const int h  = h0 + threadIdx.y;

    const float* __restrict__ A = trf + b * 16;   // wave-uniform -> scalar loads
    const float a00 = A[0], a01 = A[1], a02 = A[2],  a03 = A[3];
    const float a10 = A[4], a11 = A[5], a12 = A[6],  a13 = A[7];
    const float a20 = A[8], a21 = A[9], a22 = A[10], a23 = A[11];

    constexpr float cd = (D - 1) * 0.5f;
    constexpr float ch = (H - 1) * 0.5f;
    constexpr float cw = (W - 1) * 0.5f;

    // ---- input coords at the tile origin (voxel (d0,h0,w0)) ----
    const float md0 = (float)d0 - cd, mh0 = (float)h0 - ch, mw0 = (float)w0 - cw;
    const float od = cd + fmaf(a00, md0, fmaf(a01, mh0, fmaf(a02, mw0, a03)));
    const float oh = ch + fmaf(a10, md0, fmaf(a11, mh0, fmaf(a12, mw0, a13)));
    const float ow = cw + fmaf(a20, md0, fmaf(a21, mh0, fmaf(a22, mw0, a23)));

    // ---- block-uniform input bbox (affine -> extremes at tile corners) ----
    const float Ed = (float)(VPT - 1), Eh = (float)(TH - 1), Ew = (float)(TW - 1);
    const float dn = od + fminf(a00*Ed,0.f) + fminf(a01*Eh,0.f) + fminf(a02*Ew,0.f);
    const float dx = od + fmaxf(a00*Ed,0.f) + fmaxf(a01*Eh,0.f) + fmaxf(a02*Ew,0.f);
    const float hn = oh + fminf(a10*Ed,0.f) + fminf(a11*Eh,0.f) + fminf(a12*Ew,0.f);
    const float hx = oh + fmaxf(a10*Ed,0.f) + fmaxf(a11*Eh,0.f) + fmaxf(a12*Ew,0.f);
    const float wn = ow + fminf(a20*Ed,0.f) + fminf(a21*Eh,0.f) + fminf(a22*Ew,0.f);
    const float wx = ow + fmaxf(a20*Ed,0.f) + fmaxf(a21*Eh,0.f) + fmaxf(a22*Ew,0.f);

    // lo = min i0 over tile, hi = max i1 over tile ((int)clip is monotone in loc)
    const int lo_d = min((int)fminf(fmaxf(dn, 0.f), (float)(D-1)), D - 2);
    const int hi_d = min((int)fminf(fmaxf(dx, 0.f), (float)(D-1)), D - 2) + 1;
    const int lo_h = min((int)fminf(fmaxf(hn, 0.f), (float)(H-1)), H - 2);
    const int hi_h = min((int)fminf(fmaxf(hx, 0.f), (float)(H-1)), H - 2) + 1;
    const int lo_w = min((int)fminf(fmaxf(wn, 0.f), (float)(W-1)), W - 2);
    const int hi_w = min((int)fminf(fmaxf(wx, 0.f), (float)(W-1)), W - 2) + 1;
    const int SDn = hi_d - lo_d + 1;
    const int SHn = hi_h - lo_h + 1;
    const int SWn = hi_w - lo_w + 1;

    // ---- per-voxel coords for k=0; voxel k adds k*column0(A) ----
    const float fy = (float)threadIdx.y, fx = (float)threadIdx.x;
    float ld = fmaf(a01, fy, fmaf(a02, fx, od));
    float lh = fmaf(a11, fy, fmaf(a12, fx, oh));
    float lw = fmaf(a21, fy, fmaf(a22, fx, ow));

    const float* __restrict__ vb = vol + (size_t)b * V;
    float* ob = out + (size_t)b * V + (size_t)h * W + w;

    if (SDn <= SD_CAP && SHn <= SH_CAP && SWn <= SW_CAP) {
        // ---- LDS path: coalesced async slab staging, then LDS gather ----
        const int tid  = threadIdx.y * TW + threadIdx.x;
        const int wv   = tid >> 6;          // wave id 0..3
        const int lane = tid & 63;
        for (int z = 0; z < SDn; ++z) {
            const float* gz = vb + (size_t)(lo_d + z) * HW + lo_w;
            for (int y = wv; y < SHn; y += 4) {
                if (lane < SWn)             // SWn <= 40 < 64: single chunk
                    gload_lds_row(gz + (size_t)(lo_h + y) * W + lane,
                                  &sm[(z * SH_CAP + y) * SW_CAP]);
            }
        }
        __syncthreads();                    // drains vmcnt before s_barrier

        const int offL = (lo_d * SH_CAP + lo_h) * SW_CAP + lo_w;
#pragma unroll
        for (int k = 0; k < VPT; ++k) {
            const DimS sd = prep(ld, (float)(D - 1), D - 1);
            const DimS sh = prep(lh, (float)(H - 1), H - 1);
            const DimS sw = prep(lw, (float)(W - 1), W - 1);
            const int idx = (sd.i0 * SH_CAP + sh.i0) * SW_CAP + sw.i0 - offL;
            const float2 v00 = make_float2(sm[idx],                  sm[idx + 1]);
            const float2 v01 = make_float2(sm[idx + SW_CAP],         sm[idx + SW_CAP + 1]);
            const float2 v10 = make_float2(sm[idx + PLANE],          sm[idx + PLANE + 1]);
            const float2 v11 = make_float2(sm[idx + PLANE + SW_CAP], sm[idx + PLANE + SW_CAP + 1]);
            const float r = lerp3(sd, sh, sw, v00, v01, v10, v11);
            __builtin_nontemporal_store(r, ob + (size_t)(d0 + k) * HW);
            ld += a00; lh += a10; lw += a20;
        }
    } else {
        // ---- fallback: R4-verified global-gather path (identical arithmetic) ----
#pragma unroll
        for (int k = 0; k < VPT; ++k) {
            const DimS sd = prep(ld, (float)(D - 1), D - 1);
            const DimS sh = prep(lh, (float)(H - 1), H - 1);
            const DimS sw = prep(lw, (float)(W - 1), W - 1);
            const float r = trilerp_g(vb, sd, sh, sw);
            __builtin_nontemporal_store(r, ob + (size_t)(d0 + k) * HW);
            ld += a00; lh += a10; lw += a20;
        }
    }
}

extern "C" void kernel_launch(void* const* d_in, const int* in_sizes, int n_in,
                              void* d_out, int out_size, void* d_ws, size_t ws_size,
                              hipStream_t stream) {
    const float* vol = (const float*)d_in[0];
    const float* trf = (const float*)d_in[1];
    float* out = (float*)d_out;

    dim3 grid(GXH * GXW, D / VPT, B);   // (120, 40, 4)
    dim3 block(TW, TH, 1);
    st_affine_kernel<<<grid, block, 0, stream>>>(vol, trf, out);
}

// Round 3
// 155.442 us; speedup vs baseline: 1.1608x; 1.0367x over previous
//
#include <hip/hip_runtime.h>

// Batched 3D affine spatial transformer: vol [B=4,160,192,160,1] fp32, trf [4,4,4] fp32.
// R7: R6 (LDS slab staging) confirmed the gather-grind theory: 73->65us, VALU 36->77%.
// Now occupancy-limited (48% @ 31.7KB LDS = 5 blk/CU) with VALU stalls on top.
//  (a) shrink slab caps 14/14/40 -> 12/13/40 (24.96KB -> 6 blk/CU, 75% occ cap);
//      R6's FETCH=1.12x-ideal proves actual slabs (~7x11x37) fit with margin, and
//      overflow blocks fall back to the bit-identical global-gather path anyway.
//  (b) VALU trim: fmed3 clamp (1 instr vs min+max), block-uniform store base
//      (saddr+voffset stores), pointer-stepped staging loop.
constexpr int D = 160, H = 192, W = 160, B = 4;
constexpr int V  = D * H * W;
constexpr int HW = H * W;
constexpr int VPT = 4;                 // output voxels per thread along d
constexpr int TW  = 32, TH = 8;        // output tile in (w,h); block = (32,8)
constexpr int GXW = W / TW;            // 5
constexpr int GXH = H / TH;            // 24
constexpr int SD_CAP = 12, SH_CAP = 13, SW_CAP = 40;
constexpr int PLANE = SH_CAP * SW_CAP;            // 520 floats
constexpr int LDS_FLOATS = SD_CAP * PLANE;        // 6240 floats = 24960 B -> 6 blk/CU

struct DimS { int i0; float w0; };

// Equivalent to neuron.utils interpn clipping (verified R3):
//   c = clip(loc,0,max); i0 = min((int)c, maxi-1); i1 = i0+1; w0 = (i0+1) - c.
__device__ __forceinline__ DimS prep(float loc, float maxv, int maxi) {
    float c  = __builtin_amdgcn_fmed3f(loc, 0.0f, maxv);   // clamp, 1 VALU
    int  i0  = min((int)c, maxi - 1);
    DimS s;
    s.i0 = i0;
    s.w0 = (float)(i0 + 1) - c;
    return s;
}

__device__ __forceinline__ float lerp3(DimS sd, DimS sh, DimS sw,
                                       float2 v00, float2 v01,
                                       float2 v10, float2 v11) {
    const float pd00 = fmaf(sw.w0, v00.x - v00.y, v00.y);
    const float pd01 = fmaf(sw.w0, v01.x - v01.y, v01.y);
    const float pd10 = fmaf(sw.w0, v10.x - v10.y, v10.y);
    const float pd11 = fmaf(sw.w0, v11.x - v11.y, v11.y);
    const float q0 = fmaf(sh.w0, pd00 - pd01, pd01);
    const float q1 = fmaf(sh.w0, pd10 - pd11, pd11);
    return fmaf(sd.w0, q0 - q1, q1);
}

__device__ __forceinline__ float trilerp_g(const float* __restrict__ vb,
                                           DimS sd, DimS sh, DimS sw) {
    const float* p0 = vb + ((sd.i0 * H + sh.i0) * W + sw.i0);
    float2 v00, v01, v10, v11;
    __builtin_memcpy(&v00, p0,          8);
    __builtin_memcpy(&v01, p0 + W,      8);
    __builtin_memcpy(&v10, p0 + HW,     8);
    __builtin_memcpy(&v11, p0 + HW + W, 8);
    return lerp3(sd, sh, sw, v00, v01, v10, v11);
}

// Async global->LDS, 4B/lane. LDS dest is wave-uniform base + lane*4 (HW rule);
// inactive lanes neither load nor write.
__device__ __forceinline__ void gload_lds_row(const float* g, float* l) {
    __builtin_amdgcn_global_load_lds(
        (const __attribute__((address_space(1))) void*)g,
        (__attribute__((address_space(3))) void*)l,
        4, 0, 0);
}

__global__ __launch_bounds__(256) void st_affine_kernel(
        const float* __restrict__ vol, const float* __restrict__ trf,
        float* __restrict__ out) {
    __shared__ float sm[LDS_FLOATS];

    const int b  = blockIdx.z;
    const int d0 = blockIdx.y * VPT;
    const int hblk = blockIdx.x / GXW;
    const int wblk = blockIdx.x - hblk * GXW;
    const int w0 = wblk * TW, h0 = hblk * TH;

    const float* __restrict__ A = trf + b * 16;   // wave-uniform -> scalar loads
    const float a00 = A[0], a01 = A[1], a02 = A[2],  a03 = A[3];
    const float a10 = A[4], a11 = A[5], a12 = A[6],  a13 = A[7];
    const float a20 = A[8], a21 = A[9], a22 = A[10], a23 = A[11];

    constexpr float cd = (D - 1) * 0.5f;
    constexpr float ch = (H - 1) * 0.5f;
    constexpr float cw = (W - 1) * 0.5f;

    // ---- input coords at the tile origin (voxel (d0,h0,w0)) ----
    const float md0 = (float)d0 - cd, mh0 = (float)h0 - ch, mw0 = (float)w0 - cw;
    const float od = cd + fmaf(a00, md0, fmaf(a01, mh0, fmaf(a02, mw0, a03)));
    const float oh = ch + fmaf(a10, md0, fmaf(a11, mh0, fmaf(a12, mw0, a13)));
    const float ow = cw + fmaf(a20, md0, fmaf(a21, mh0, fmaf(a22, mw0, a23)));

    // ---- block-uniform input bbox (affine -> extremes at tile corners) ----
    const float Ed = (float)(VPT - 1), Eh = (float)(TH - 1), Ew = (float)(TW - 1);
    const float dn = od + fminf(a00*Ed,0.f) + fminf(a01*Eh,0.f) + fminf(a02*Ew,0.f);
    const float dx = od + fmaxf(a00*Ed,0.f) + fmaxf(a01*Eh,0.f) + fmaxf(a02*Ew,0.f);
    const float hn = oh + fminf(a10*Ed,0.f) + fminf(a11*Eh,0.f) + fminf(a12*Ew,0.f);
    const float hx = oh + fmaxf(a10*Ed,0.f) + fmaxf(a11*Eh,0.f) + fmaxf(a12*Ew,0.f);
    const float wn = ow + fminf(a20*Ed,0.f) + fminf(a21*Eh,0.f) + fminf(a22*Ew,0.f);
    const float wx = ow + fmaxf(a20*Ed,0.f) + fmaxf(a21*Eh,0.f) + fmaxf(a22*Ew,0.f);

    // lo = min i0 over tile, hi = max i1 over tile ((int)clip is monotone in loc)
    const int lo_d = min((int)__builtin_amdgcn_fmed3f(dn, 0.f, (float)(D-1)), D - 2);
    const int hi_d = min((int)__builtin_amdgcn_fmed3f(dx, 0.f, (float)(D-1)), D - 2) + 1;
    const int lo_h = min((int)__builtin_amdgcn_fmed3f(hn, 0.f, (float)(H-1)), H - 2);
    const int hi_h = min((int)__builtin_amdgcn_fmed3f(hx, 0.f, (float)(H-1)), H - 2) + 1;
    const int lo_w = min((int)__builtin_amdgcn_fmed3f(wn, 0.f, (float)(W-1)), W - 2);
    const int hi_w = min((int)__builtin_amdgcn_fmed3f(wx, 0.f, (float)(W-1)), W - 2) + 1;
    const int SDn = hi_d - lo_d + 1;
    const int SHn = hi_h - lo_h + 1;
    const int SWn = hi_w - lo_w + 1;

    // ---- per-voxel coords for k=0; voxel k adds k*column0(A) ----
    const float fy = (float)threadIdx.y, fx = (float)threadIdx.x;
    float ld = fmaf(a01, fy, fmaf(a02, fx, od));
    float lh = fmaf(a11, fy, fmaf(a12, fx, oh));
    float lw = fmaf(a21, fy, fmaf(a22, fx, ow));

    const float* __restrict__ vb = vol + (size_t)b * V;
    // Block-uniform store base (SGPR) + per-thread 32-bit offset -> saddr stores.
    float* __restrict__ ob = out + (size_t)b * V + (size_t)d0 * HW;
    const int oofs = (h0 + threadIdx.y) * W + w0 + threadIdx.x;

    if (SDn <= SD_CAP && SHn <= SH_CAP && SWn <= SW_CAP) {
        // ---- LDS path: coalesced async slab staging, then LDS gather ----
        const int tid  = threadIdx.y * TW + threadIdx.x;
        const int wv   = tid >> 6;          // wave id 0..3
        const int lane = tid & 63;
        const bool act = lane < SWn;        // SWn <= 40 < 64: single chunk per row
        const float* gz = vb + (size_t)lo_d * HW + (size_t)lo_h * W + lo_w;
        float* lz = sm;
        for (int z = 0; z < SDn; ++z) {
            for (int y = wv; y < SHn; y += 4) {
                if (act)
                    gload_lds_row(gz + (size_t)y * W + lane, lz + y * SW_CAP);
            }
            gz += HW;
            lz += PLANE;
        }
        __syncthreads();                    // drains vmcnt before s_barrier

        const int offL = (lo_d * SH_CAP + lo_h) * SW_CAP + lo_w;
#pragma unroll
        for (int k = 0; k < VPT; ++k) {
            const DimS sd = prep(ld, (float)(D - 1), D - 1);
            const DimS sh = prep(lh, (float)(H - 1), H - 1);
            const DimS sw = prep(lw, (float)(W - 1), W - 1);
            const int idx = (sd.i0 * SH_CAP + sh.i0) * SW_CAP + sw.i0 - offL;
            const float2 v00 = make_float2(sm[idx],                  sm[idx + 1]);
            const float2 v01 = make_float2(sm[idx + SW_CAP],         sm[idx + SW_CAP + 1]);
            const float2 v10 = make_float2(sm[idx + PLANE],          sm[idx + PLANE + 1]);
            const float2 v11 = make_float2(sm[idx + PLANE + SW_CAP], sm[idx + PLANE + SW_CAP + 1]);
            const float r = lerp3(sd, sh, sw, v00, v01, v10, v11);
            __builtin_nontemporal_store(r, ob + oofs + k * HW);
            ld += a00; lh += a10; lw += a20;
        }
    } else {
        // ---- fallback: R4-verified global-gather path (identical arithmetic) ----
#pragma unroll
        for (int k = 0; k < VPT; ++k) {
            const DimS sd = prep(ld, (float)(D - 1), D - 1);
            const DimS sh = prep(lh, (float)(H - 1), H - 1);
            const DimS sw = prep(lw, (float)(W - 1), W - 1);
            const float r = trilerp_g(vb, sd, sh, sw);
            __builtin_nontemporal_store(r, ob + oofs + k * HW);
            ld += a00; lh += a10; lw += a20;
        }
    }
}

extern "C" void kernel_launch(void* const* d_in, const int* in_sizes, int n_in,
                              void* d_out, int out_size, void* d_ws, size_t ws_size,
                              hipStream_t stream) {
    const float* vol = (const float*)d_in[0];
    const float* trf = (const float*)d_in[1];
    float* out = (float*)d_out;

    dim3 grid(GXH * GXW, D / VPT, B);   // (120, 40, 4)
    dim3 block(TW, TH, 1);
    st_affine_kernel<<<grid, block, 0, stream>>>(vol, trf, out);
}

// Round 4
// 151.086 us; speedup vs baseline: 1.1943x; 1.0288x over previous
//
#include <hip/hip_runtime.h>

// Batched 3D affine spatial transformer: vol [B=4,160,192,160,1] fp32, trf [4,4,4] fp32.
// R8: R7 hit 59.5us, VALU(reported) 81% -- but corrected for the gfx94x VALUBusy
// formula (4cyc vs gfx950's 2cyc issue) true VALU ~40%; LDS ~25%, HBM ~44%. Nothing
// saturated => concurrency-bound on per-block barrier drains. R7's FETCH was
// bit-identical to R6 => zero fallback at caps 12/13/40, so margin remains.
// Single change: caps 12/13/40 -> 10/12/40 = 19.2KB LDS -> 8 blocks/CU, hitting the
// 32-wave/CU slot cap (100% occupancy). Fallback (bit-identical global path) covers
// any block whose slab exceeds the caps; FETCH_SIZE is the tripwire for that.
constexpr int D = 160, H = 192, W = 160, B = 4;
constexpr int V  = D * H * W;
constexpr int HW = H * W;
constexpr int VPT = 4;                 // output voxels per thread along d
constexpr int TW  = 32, TH = 8;        // output tile in (w,h); block = (32,8)
constexpr int GXW = W / TW;            // 5
constexpr int GXH = H / TH;            // 24
constexpr int SD_CAP = 10, SH_CAP = 12, SW_CAP = 40;
constexpr int PLANE = SH_CAP * SW_CAP;            // 480 floats
constexpr int LDS_FLOATS = SD_CAP * PLANE;        // 4800 floats = 19200 B -> 8 blk/CU

struct DimS { int i0; float w0; };

// Equivalent to neuron.utils interpn clipping (verified R3):
//   c = clip(loc,0,max); i0 = min((int)c, maxi-1); i1 = i0+1; w0 = (i0+1) - c.
__device__ __forceinline__ DimS prep(float loc, float maxv, int maxi) {
    float c  = __builtin_amdgcn_fmed3f(loc, 0.0f, maxv);   // clamp, 1 VALU
    int  i0  = min((int)c, maxi - 1);
    DimS s;
    s.i0 = i0;
    s.w0 = (float)(i0 + 1) - c;
    return s;
}

__device__ __forceinline__ float lerp3(DimS sd, DimS sh, DimS sw,
                                       float2 v00, float2 v01,
                                       float2 v10, float2 v11) {
    const float pd00 = fmaf(sw.w0, v00.x - v00.y, v00.y);
    const float pd01 = fmaf(sw.w0, v01.x - v01.y, v01.y);
    const float pd10 = fmaf(sw.w0, v10.x - v10.y, v10.y);
    const float pd11 = fmaf(sw.w0, v11.x - v11.y, v11.y);
    const float q0 = fmaf(sh.w0, pd00 - pd01, pd01);
    const float q1 = fmaf(sh.w0, pd10 - pd11, pd11);
    return fmaf(sd.w0, q0 - q1, q1);
}

__device__ __forceinline__ float trilerp_g(const float* __restrict__ vb,
                                           DimS sd, DimS sh, DimS sw) {
    const float* p0 = vb + ((sd.i0 * H + sh.i0) * W + sw.i0);
    float2 v00, v01, v10, v11;
    __builtin_memcpy(&v00, p0,          8);
    __builtin_memcpy(&v01, p0 + W,      8);
    __builtin_memcpy(&v10, p0 + HW,     8);
    __builtin_memcpy(&v11, p0 + HW + W, 8);
    return lerp3(sd, sh, sw, v00, v01, v10, v11);
}

// Async global->LDS, 4B/lane. LDS dest is wave-uniform base + lane*4 (HW rule);
// inactive lanes neither load nor write.
__device__ __forceinline__ void gload_lds_row(const float* g, float* l) {
    __builtin_amdgcn_global_load_lds(
        (const __attribute__((address_space(1))) void*)g,
        (__attribute__((address_space(3))) void*)l,
        4, 0, 0);
}

__global__ __launch_bounds__(256) void st_affine_kernel(
        const float* __restrict__ vol, const float* __restrict__ trf,
        float* __restrict__ out) {
    __shared__ float sm[LDS_FLOATS];

    const int b  = blockIdx.z;
    const int d0 = blockIdx.y * VPT;
    const int hblk = blockIdx.x / GXW;
    const int wblk = blockIdx.x - hblk * GXW;
    const int w0 = wblk * TW, h0 = hblk * TH;

    const float* __restrict__ A = trf + b * 16;   // wave-uniform -> scalar loads
    const float a00 = A[0], a01 = A[1], a02 = A[2],  a03 = A[3];
    const float a10 = A[4], a11 = A[5], a12 = A[6],  a13 = A[7];
    const float a20 = A[8], a21 = A[9], a22 = A[10], a23 = A[11];

    constexpr float cd = (D - 1) * 0.5f;
    constexpr float ch = (H - 1) * 0.5f;
    constexpr float cw = (W - 1) * 0.5f;

    // ---- input coords at the tile origin (voxel (d0,h0,w0)) ----
    const float md0 = (float)d0 - cd, mh0 = (float)h0 - ch, mw0 = (float)w0 - cw;
    const float od = cd + fmaf(a00, md0, fmaf(a01, mh0, fmaf(a02, mw0, a03)));
    const float oh = ch + fmaf(a10, md0, fmaf(a11, mh0, fmaf(a12, mw0, a13)));
    const float ow = cw + fmaf(a20, md0, fmaf(a21, mh0, fmaf(a22, mw0, a23)));

    // ---- block-uniform input bbox (affine -> extremes at tile corners) ----
    const float Ed = (float)(VPT - 1), Eh = (float)(TH - 1), Ew = (float)(TW - 1);
    const float dn = od + fminf(a00*Ed,0.f) + fminf(a01*Eh,0.f) + fminf(a02*Ew,0.f);
    const float dx = od + fmaxf(a00*Ed,0.f) + fmaxf(a01*Eh,0.f) + fmaxf(a02*Ew,0.f);
    const float hn = oh + fminf(a10*Ed,0.f) + fminf(a11*Eh,0.f) + fminf(a12*Ew,0.f);
    const float hx = oh + fmaxf(a10*Ed,0.f) + fmaxf(a11*Eh,0.f) + fmaxf(a12*Ew,0.f);
    const float wn = ow + fminf(a20*Ed,0.f) + fminf(a21*Eh,0.f) + fminf(a22*Ew,0.f);
    const float wx = ow + fmaxf(a20*Ed,0.f) + fmaxf(a21*Eh,0.f) + fmaxf(a22*Ew,0.f);

    // lo = min i0 over tile, hi = max i1 over tile ((int)clip is monotone in loc)
    const int lo_d = min((int)__builtin_amdgcn_fmed3f(dn, 0.f, (float)(D-1)), D - 2);
    const int hi_d = min((int)__builtin_amdgcn_fmed3f(dx, 0.f, (float)(D-1)), D - 2) + 1;
    const int lo_h = min((int)__builtin_amdgcn_fmed3f(hn, 0.f, (float)(H-1)), H - 2);
    const int hi_h = min((int)__builtin_amdgcn_fmed3f(hx, 0.f, (float)(H-1)), H - 2) + 1;
    const int lo_w = min((int)__builtin_amdgcn_fmed3f(wn, 0.f, (float)(W-1)), W - 2);
    const int hi_w = min((int)__builtin_amdgcn_fmed3f(wx, 0.f, (float)(W-1)), W - 2) + 1;
    const int SDn = hi_d - lo_d + 1;
    const int SHn = hi_h - lo_h + 1;
    const int SWn = hi_w - lo_w + 1;

    // ---- per-voxel coords for k=0; voxel k adds k*column0(A) ----
    const float fy = (float)threadIdx.y, fx = (float)threadIdx.x;
    float ld = fmaf(a01, fy, fmaf(a02, fx, od));
    float lh = fmaf(a11, fy, fmaf(a12, fx, oh));
    float lw = fmaf(a21, fy, fmaf(a22, fx, ow));

    const float* __restrict__ vb = vol + (size_t)b * V;
    // Block-uniform store base (SGPR) + per-thread 32-bit offset -> saddr stores.
    float* __restrict__ ob = out + (size_t)b * V + (size_t)d0 * HW;
    const int oofs = (h0 + threadIdx.y) * W + w0 + threadIdx.x;

    if (SDn <= SD_CAP && SHn <= SH_CAP && SWn <= SW_CAP) {
        // ---- LDS path: coalesced async slab staging, then LDS gather ----
        const int tid  = threadIdx.y * TW + threadIdx.x;
        const int wv   = tid >> 6;          // wave id 0..3
        const int lane = tid & 63;
        const bool act = lane < SWn;        // SWn <= 40 < 64: single chunk per row
        const float* gz = vb + (size_t)lo_d * HW + (size_t)lo_h * W + lo_w;
        float* lz = sm;
        for (int z = 0; z < SDn; ++z) {
            for (int y = wv; y < SHn; y += 4) {
                if (act)
                    gload_lds_row(gz + (size_t)y * W + lane, lz + y * SW_CAP);
            }
            gz += HW;
            lz += PLANE;
        }
        __syncthreads();                    // drains vmcnt before s_barrier

        const int offL = (lo_d * SH_CAP + lo_h) * SW_CAP + lo_w;
#pragma unroll
        for (int k = 0; k < VPT; ++k) {
            const DimS sd = prep(ld, (float)(D - 1), D - 1);
            const DimS sh = prep(lh, (float)(H - 1), H - 1);
            const DimS sw = prep(lw, (float)(W - 1), W - 1);
            const int idx = (sd.i0 * SH_CAP + sh.i0) * SW_CAP + sw.i0 - offL;
            const float2 v00 = make_float2(sm[idx],                  sm[idx + 1]);
            const float2 v01 = make_float2(sm[idx + SW_CAP],         sm[idx + SW_CAP + 1]);
            const float2 v10 = make_float2(sm[idx + PLANE],          sm[idx + PLANE + 1]);
            const float2 v11 = make_float2(sm[idx + PLANE + SW_CAP], sm[idx + PLANE + SW_CAP + 1]);
            const float r = lerp3(sd, sh, sw, v00, v01, v10, v11);
            __builtin_nontemporal_store(r, ob + oofs + k * HW);
            ld += a00; lh += a10; lw += a20;
        }
    } else {
        // ---- fallback: R4-verified global-gather path (identical arithmetic) ----
#pragma unroll
        for (int k = 0; k < VPT; ++k) {
            const DimS sd = prep(ld, (float)(D - 1), D - 1);
            const DimS sh = prep(lh, (float)(H - 1), H - 1);
            const DimS sw = prep(lw, (float)(W - 1), W - 1);
            const float r = trilerp_g(vb, sd, sh, sw);
            __builtin_nontemporal_store(r, ob + oofs + k * HW);
            ld += a00; lh += a10; lw += a20;
        }
    }
}

extern "C" void kernel_launch(void* const* d_in, const int* in_sizes, int n_in,
                              void* d_out, int out_size, void* d_ws, size_t ws_size,
                              hipStream_t stream) {
    const float* vol = (const float*)d_in[0];
    const float* trf = (const float*)d_in[1];
    float* out = (float*)d_out;

    dim3 grid(GXH * GXW, D / VPT, B);   // (120, 40, 4)
    dim3 block(TW, TH, 1);
    st_affine_kernel<<<grid, block, 0, stream>>>(vol, trf, out);
}